// Round 1
// baseline (85.846 us; speedup 1.0000x reference)
//
#include <hip/hip_runtime.h>
#include <stdint.h>

#define MARGIN 0.3f
#define NROWS 4096
#define DIM   2048
#define BT    128
#define BK    32
#define NB    (NROWS / BT)          // 32
#define NBLK  (NB * (NB + 1) / 2)   // 528

typedef float f32x4 __attribute__((ext_vector_type(4)));
typedef short s16x8 __attribute__((ext_vector_type(8)));

__device__ __forceinline__ ushort f32_to_bf16(float f) {
  uint32_t u = __float_as_uint(f);
  return (ushort)((u + 0x7FFFu + ((u >> 16) & 1u)) >> 16);  // RNE, no NaN in data
}

// ---------------------------------------------------------------------------
// prep: row L2-norm. FLY=0: write normalized bf16 matrix. FLY=1: write 1/norm.
// Also zeroes the accumulators (block 0, thread 0).
// ---------------------------------------------------------------------------
template <int FLY>
__global__ __launch_bounds__(256) void prep_kernel(const float* __restrict__ in,
                                                   ushort* __restrict__ pn,
                                                   float* __restrict__ invn,
                                                   float* __restrict__ accum) {
  const int row = blockIdx.x;
  const int tid = threadIdx.x;
  if (row == 0 && tid == 0) { accum[0] = 0.f; accum[1] = 0.f; }

  const float4* rp = (const float4*)(in + (size_t)row * DIM);
  float4 v0 = rp[tid * 2];
  float4 v1 = rp[tid * 2 + 1];
  float ss = v0.x*v0.x + v0.y*v0.y + v0.z*v0.z + v0.w*v0.w
           + v1.x*v1.x + v1.y*v1.y + v1.z*v1.z + v1.w*v1.w;
  #pragma unroll
  for (int off = 32; off; off >>= 1) ss += __shfl_down(ss, off);

  __shared__ float wred[4];
  __shared__ float stot;
  const int lane = tid & 63, w = tid >> 6;
  if (lane == 0) wred[w] = ss;
  __syncthreads();
  if (tid == 0) stot = wred[0] + wred[1] + wred[2] + wred[3];
  __syncthreads();
  const float inv = 1.0f / fmaxf(sqrtf(stot), 1e-12f);

  if (FLY) {
    if (tid == 0) invn[row] = inv;
  } else {
    int4 pack;
    ushort* h = (ushort*)&pack;
    h[0] = f32_to_bf16(v0.x * inv); h[1] = f32_to_bf16(v0.y * inv);
    h[2] = f32_to_bf16(v0.z * inv); h[3] = f32_to_bf16(v0.w * inv);
    h[4] = f32_to_bf16(v1.x * inv); h[5] = f32_to_bf16(v1.y * inv);
    h[6] = f32_to_bf16(v1.z * inv); h[7] = f32_to_bf16(v1.w * inv);
    *(int4*)(pn + (size_t)row * DIM + tid * 8) = pack;
  }
}

// ---------------------------------------------------------------------------
// tri_gemm: one block per upper-triangular 128x128 super-tile of sim = Pn Pn^T.
// 4 waves (2x2), each wave a 64x64 sub-tile as 4x4 fragments of 16x16x32 MFMA.
// Epilogue masks (i < j && s > MARGIN), block-reduces, atomically accumulates.
// ---------------------------------------------------------------------------
template <int FLY>
__global__ __launch_bounds__(256) void tri_gemm(const float* __restrict__ inF,
                                                const ushort* __restrict__ pn,
                                                const float* __restrict__ invn,
                                                float* __restrict__ accum) {
  // linear block id -> (bi, bj) with bi <= bj
  int t = blockIdx.x, bi = 0;
  while (t >= NB - bi) { t -= NB - bi; ++bi; }
  const int bj = bi + t;

  __shared__ __align__(16) ushort Asm[BT * BK];
  __shared__ __align__(16) ushort Bsm[BT * BK];

  const int tid  = threadIdx.x;
  const int lane = tid & 63;
  const int w    = tid >> 6;
  const int wr   = w >> 1, wc = w & 1;

  f32x4 acc[4][4] = {};

  const int rowA = bi * BT, rowB = bj * BT;

  for (int k0 = 0; k0 < DIM; k0 += BK) {
    if (k0) __syncthreads();  // protect LDS from overwrite while prior reads in flight
    if (FLY == 0) {
      // 16 KB total = 1024 chunks of 16B; 256 threads x 4 chunks
      #pragma unroll
      for (int p = 0; p < 4; ++p) {
        int c   = p * 256 + tid;     // 0..1023
        int isB = c >> 9;
        int cc  = c & 511;
        int r   = cc >> 2;           // 0..127
        int k16 = cc & 3;            // 16B unit within 64B row
        const int grow = (isB ? rowB : rowA) + r;
        int4 v = *(const int4*)(pn + (size_t)grow * DIM + k0 + k16 * 8);
        *(int4*)((isB ? Bsm : Asm) + r * BK + k16 * 8) = v;
      }
    } else {
      // f32 source, convert on the fly: 32 KB = 2048 chunks of 4 floats
      #pragma unroll
      for (int p = 0; p < 8; ++p) {
        int c   = p * 256 + tid;     // 0..2047
        int isB = c >> 10;
        int cc  = c & 1023;
        int r   = cc >> 3;           // 0..127
        int k4  = cc & 7;            // 4-float unit within 32-f32 row
        const int grow = (isB ? rowB : rowA) + r;
        float4 v = *(const float4*)(inF + (size_t)grow * DIM + k0 + k4 * 4);
        int2 pack;
        ushort* h = (ushort*)&pack;
        h[0] = f32_to_bf16(v.x); h[1] = f32_to_bf16(v.y);
        h[2] = f32_to_bf16(v.z); h[3] = f32_to_bf16(v.w);
        *(int2*)((isB ? Bsm : Asm) + r * BK + k4 * 4) = pack;
      }
    }
    __syncthreads();

    s16x8 af[4], bfv[4];
    #pragma unroll
    for (int m = 0; m < 4; ++m)
      af[m] = *(const s16x8*)(Asm + (wr * 64 + m * 16 + (lane & 15)) * BK + (lane >> 4) * 8);
    #pragma unroll
    for (int n = 0; n < 4; ++n)
      bfv[n] = *(const s16x8*)(Bsm + (wc * 64 + n * 16 + (lane & 15)) * BK + (lane >> 4) * 8);

    #pragma unroll
    for (int m = 0; m < 4; ++m)
      #pragma unroll
      for (int n = 0; n < 4; ++n)
        acc[m][n] = __builtin_amdgcn_mfma_f32_16x16x32_bf16(af[m], bfv[n], acc[m][n], 0, 0, 0);
  }

  // ---- epilogue: mask + reduce ----
  float lsum = 0.f, lcnt = 0.f;
  const int gib = rowA + wr * 64;
  const int gjb = rowB + wc * 64;
  #pragma unroll
  for (int m = 0; m < 4; ++m) {
    #pragma unroll
    for (int n = 0; n < 4; ++n) {
      #pragma unroll
      for (int r = 0; r < 4; ++r) {
        int gi = gib + m * 16 + (lane >> 4) * 4 + r;
        int gj = gjb + n * 16 + (lane & 15);
        float s = acc[m][n][r];
        if (FLY) s *= invn[gi] * invn[gj];
        if (gi < gj && s > MARGIN) { lsum += s - MARGIN; lcnt += 1.f; }
      }
    }
  }
  #pragma unroll
  for (int off = 32; off; off >>= 1) {
    lsum += __shfl_down(lsum, off);
    lcnt += __shfl_down(lcnt, off);
  }
  __shared__ float rs[4], rc[4];
  if (lane == 0) { rs[w] = lsum; rc[w] = lcnt; }
  __syncthreads();
  if (tid == 0) {
    atomicAdd(&accum[0], rs[0] + rs[1] + rs[2] + rs[3]);
    atomicAdd(&accum[1], rc[0] + rc[1] + rc[2] + rc[3]);
  }
}

__global__ void finalize_kernel(const float* __restrict__ accum, float* __restrict__ out) {
  if (threadIdx.x == 0) out[0] = (accum[1] < 0.5f) ? 0.0f : accum[0] / accum[1];
}

extern "C" void kernel_launch(void* const* d_in, const int* in_sizes, int n_in,
                              void* d_out, int out_size, void* d_ws, size_t ws_size,
                              hipStream_t stream) {
  const float* in = (const float*)d_in[0];
  float* out = (float*)d_out;
  const size_t pn_bytes = (size_t)NROWS * DIM * sizeof(ushort);

  if (ws_size >= pn_bytes + 2 * sizeof(float)) {
    // primary path: precomputed normalized bf16 matrix in workspace
    ushort* pn   = (ushort*)d_ws;
    float* accum = (float*)((char*)d_ws + pn_bytes);
    prep_kernel<0><<<NROWS, 256, 0, stream>>>(in, pn, nullptr, accum);
    tri_gemm<0><<<NBLK, 256, 0, stream>>>(in, pn, nullptr, accum);
    finalize_kernel<<<1, 64, 0, stream>>>(accum, out);
  } else {
    // fallback: tiny workspace — convert on the fly, scale at epilogue
    float* invn  = (float*)d_ws;
    float* accum = (float*)((char*)d_ws + NROWS * sizeof(float));
    prep_kernel<1><<<NROWS, 256, 0, stream>>>(in, nullptr, invn, accum);
    tri_gemm<1><<<NBLK, 256, 0, stream>>>(in, nullptr, invn, accum);
    finalize_kernel<<<1, 64, 0, stream>>>(accum, out);
  }
}

// Round 2
// 66.214 us; speedup vs baseline: 1.2965x; 1.2965x over previous
//
#include <hip/hip_runtime.h>
#include <stdint.h>

#define MARGIN 0.3f
#define NROWS 4096
#define DIM   2048
#define BT    128
#define BK    64
#define NB    (NROWS / BT)          // 32
#define NBLK  (NB * (NB + 1) / 2)   // 528

typedef float f32x4 __attribute__((ext_vector_type(4)));
typedef short s16x8 __attribute__((ext_vector_type(8)));

__device__ __forceinline__ ushort f32_to_bf16(float f) {
  uint32_t u = __float_as_uint(f);
  return (ushort)((u + 0x7FFFu + ((u >> 16) & 1u)) >> 16);  // RNE, no NaN in data
}

// async global->LDS, 16B per lane. LDS dest is wave-uniform base; lane l
// writes base + l*16 (linear). Swizzle is carried on the GLOBAL source addr.
__device__ __forceinline__ void async_load16(const ushort* g, ushort* l) {
  __builtin_amdgcn_global_load_lds(
      (const __attribute__((address_space(1))) uint32_t*)g,
      (__attribute__((address_space(3))) uint32_t*)l, 16, 0, 0);
}

// ---------------------------------------------------------------------------
// prep: row L2-norm. FLY=0: write normalized bf16 matrix. FLY=1: write 1/norm.
// Also zeroes the accumulators (block 0, thread 0).
// ---------------------------------------------------------------------------
template <int FLY>
__global__ __launch_bounds__(256) void prep_kernel(const float* __restrict__ in,
                                                   ushort* __restrict__ pn,
                                                   float* __restrict__ invn,
                                                   float* __restrict__ accum) {
  const int row = blockIdx.x;
  const int tid = threadIdx.x;
  if (row == 0 && tid == 0) { accum[0] = 0.f; accum[1] = 0.f; }

  const float4* rp = (const float4*)(in + (size_t)row * DIM);
  float4 v0 = rp[tid * 2];
  float4 v1 = rp[tid * 2 + 1];
  float ss = v0.x*v0.x + v0.y*v0.y + v0.z*v0.z + v0.w*v0.w
           + v1.x*v1.x + v1.y*v1.y + v1.z*v1.z + v1.w*v1.w;
  #pragma unroll
  for (int off = 32; off; off >>= 1) ss += __shfl_down(ss, off);

  __shared__ float wred[4];
  __shared__ float stot;
  const int lane = tid & 63, w = tid >> 6;
  if (lane == 0) wred[w] = ss;
  __syncthreads();
  if (tid == 0) stot = wred[0] + wred[1] + wred[2] + wred[3];
  __syncthreads();
  const float inv = 1.0f / fmaxf(sqrtf(stot), 1e-12f);

  if (FLY) {
    if (tid == 0) invn[row] = inv;
  } else {
    int4 pack;
    ushort* h = (ushort*)&pack;
    h[0] = f32_to_bf16(v0.x * inv); h[1] = f32_to_bf16(v0.y * inv);
    h[2] = f32_to_bf16(v0.z * inv); h[3] = f32_to_bf16(v0.w * inv);
    h[4] = f32_to_bf16(v1.x * inv); h[5] = f32_to_bf16(v1.y * inv);
    h[6] = f32_to_bf16(v1.z * inv); h[7] = f32_to_bf16(v1.w * inv);
    *(int4*)(pn + (size_t)row * DIM + tid * 8) = pack;
  }
}

// ---------------------------------------------------------------------------
// tri_gemm: one block per upper-triangular 128x128 super-tile of sim = Pn Pn^T.
// 4 waves (2x2), each wave a 64x64 sub-tile as 4x4 fragments of 16x16x32 MFMA,
// BK=64 K-steps. Staging via global_load_lds (16B/lane, linear LDS dest) with
// the k-slot XOR swizzle pre-applied on the global source address; fragment
// ds_read_b128 applies the same XOR -> ~2-way banks (free).
// Epilogue masks (i < j && s > MARGIN), block-reduces, atomically accumulates.
// ---------------------------------------------------------------------------
template <int FLY>
__global__ __launch_bounds__(256) void tri_gemm(const float* __restrict__ inF,
                                                const ushort* __restrict__ pn,
                                                const float* __restrict__ invn,
                                                float* __restrict__ accum) {
  // linear block id -> (bi, bj) with bi <= bj
  int t = blockIdx.x, bi = 0;
  while (t >= NB - bi) { t -= NB - bi; ++bi; }
  const int bj = bi + t;

  __shared__ __align__(16) ushort Asm[BT * BK];   // 16 KB, rows of 128 B
  __shared__ __align__(16) ushort Bsm[BT * BK];   // 16 KB

  const int tid  = threadIdx.x;
  const int lane = tid & 63;
  const int w    = tid >> 6;
  const int wr   = w >> 1, wc = w & 1;

  f32x4 acc[4][4] = {};

  const int rowA = bi * BT, rowB = bj * BT;

  // staging geometry: 1 KB chunk = 8 rows x 128 B; lane l -> row +(l>>3),
  // stored slot (l&7); global true-k slot = (l&7) ^ (l>>3)   [row&7 == l>>3]
  const int srow  = (lane >> 3);            // row within 8-row chunk
  const int gslot = (lane & 7) ^ srow;      // swizzled 16B slot in source row

  for (int k0 = 0; k0 < DIM; k0 += BK) {
    if (k0) __syncthreads();  // prior reads done before LDS overwrite
    if (FLY == 0) {
      #pragma unroll
      for (int q = 0; q < 4; ++q) {
        const int r = w * 32 + q * 8;       // chunk base row (multiple of 8)
        async_load16(pn + (size_t)(rowA + r + srow) * DIM + k0 + gslot * 8,
                     Asm + r * BK);
        async_load16(pn + (size_t)(rowB + r + srow) * DIM + k0 + gslot * 8,
                     Bsm + r * BK);
      }
    } else {
      // f32 source, convert+swizzle on the fly (reg staging):
      // 2048 dst units of 16B (8 bf16) = 32B src each; 8 units/thread
      #pragma unroll
      for (int p = 0; p < 8; ++p) {
        int c   = p * 256 + tid;            // 0..2047
        int isB = c >> 10;
        int cc  = c & 1023;
        int r   = cc >> 3;                  // 0..127
        int s   = cc & 7;                   // true k slot
        const int grow = (isB ? rowB : rowA) + r;
        const float4* src = (const float4*)(inF + (size_t)grow * DIM + k0 + s * 8);
        float4 v0 = src[0], v1 = src[1];
        int4 pack;
        ushort* h = (ushort*)&pack;
        h[0] = f32_to_bf16(v0.x); h[1] = f32_to_bf16(v0.y);
        h[2] = f32_to_bf16(v0.z); h[3] = f32_to_bf16(v0.w);
        h[4] = f32_to_bf16(v1.x); h[5] = f32_to_bf16(v1.y);
        h[6] = f32_to_bf16(v1.z); h[7] = f32_to_bf16(v1.w);
        *(int4*)((isB ? Bsm : Asm) + r * BK + (s ^ (r & 7)) * 8) = pack;
      }
    }
    __syncthreads();  // drains vmcnt(0): global_load_lds data visible

    s16x8 af[2][4], bfv[2][4];
    const int fr = lane & 15, hi = lane >> 4;
    #pragma unroll
    for (int kk = 0; kk < 2; ++kk) {
      #pragma unroll
      for (int m = 0; m < 4; ++m) {
        const int ra = wr * 64 + m * 16 + fr;
        af[kk][m] = *(const s16x8*)(Asm + ra * BK + ((kk * 4 + hi) ^ (ra & 7)) * 8);
        const int rb = wc * 64 + m * 16 + fr;
        bfv[kk][m] = *(const s16x8*)(Bsm + rb * BK + ((kk * 4 + hi) ^ (rb & 7)) * 8);
      }
    }
    #pragma unroll
    for (int kk = 0; kk < 2; ++kk)
      #pragma unroll
      for (int m = 0; m < 4; ++m)
        #pragma unroll
        for (int n = 0; n < 4; ++n)
          acc[m][n] = __builtin_amdgcn_mfma_f32_16x16x32_bf16(af[kk][m], bfv[kk][n],
                                                              acc[m][n], 0, 0, 0);
  }

  // ---- epilogue: mask + reduce ----
  float lsum = 0.f, lcnt = 0.f;
  const int gib = rowA + wr * 64;
  const int gjb = rowB + wc * 64;
  #pragma unroll
  for (int m = 0; m < 4; ++m) {
    #pragma unroll
    for (int n = 0; n < 4; ++n) {
      #pragma unroll
      for (int r = 0; r < 4; ++r) {
        int gi = gib + m * 16 + (lane >> 4) * 4 + r;
        int gj = gjb + n * 16 + (lane & 15);
        float s = acc[m][n][r];
        if (FLY) s *= invn[gi] * invn[gj];
        if (gi < gj && s > MARGIN) { lsum += s - MARGIN; lcnt += 1.f; }
      }
    }
  }
  #pragma unroll
  for (int off = 32; off; off >>= 1) {
    lsum += __shfl_down(lsum, off);
    lcnt += __shfl_down(lcnt, off);
  }
  __shared__ float rs[4], rc[4];
  if (lane == 0) { rs[w] = lsum; rc[w] = lcnt; }
  __syncthreads();
  if (tid == 0) {
    atomicAdd(&accum[0], rs[0] + rs[1] + rs[2] + rs[3]);
    atomicAdd(&accum[1], rc[0] + rc[1] + rc[2] + rc[3]);
  }
}

__global__ void finalize_kernel(const float* __restrict__ accum, float* __restrict__ out) {
  if (threadIdx.x == 0) out[0] = (accum[1] < 0.5f) ? 0.0f : accum[0] / accum[1];
}

extern "C" void kernel_launch(void* const* d_in, const int* in_sizes, int n_in,
                              void* d_out, int out_size, void* d_ws, size_t ws_size,
                              hipStream_t stream) {
  const float* in = (const float*)d_in[0];
  float* out = (float*)d_out;
  const size_t pn_bytes = (size_t)NROWS * DIM * sizeof(ushort);

  if (ws_size >= pn_bytes + 2 * sizeof(float)) {
    // primary path: precomputed normalized bf16 matrix in workspace
    ushort* pn   = (ushort*)d_ws;
    float* accum = (float*)((char*)d_ws + pn_bytes);
    prep_kernel<0><<<NROWS, 256, 0, stream>>>(in, pn, nullptr, accum);
    tri_gemm<0><<<NBLK, 256, 0, stream>>>(in, pn, nullptr, accum);
    finalize_kernel<<<1, 64, 0, stream>>>(accum, out);
  } else {
    // fallback: tiny workspace — convert on the fly, scale at epilogue
    float* invn  = (float*)d_ws;
    float* accum = (float*)((char*)d_ws + NROWS * sizeof(float));
    prep_kernel<1><<<NROWS, 256, 0, stream>>>(in, nullptr, invn, accum);
    tri_gemm<1><<<NBLK, 256, 0, stream>>>(in, nullptr, invn, accum);
    finalize_kernel<<<1, 64, 0, stream>>>(accum, out);
  }
}